// Round 2
// baseline (697.417 us; speedup 1.0000x reference)
//
#include <hip/hip_runtime.h>
#include <hip/hip_bf16.h>

// ---------------------------------------------------------------------------
// TemporallyCalibratedTransformerLayer  (B=64, N=197, C=768, H=12, Dh=64,
// T_TOK=4, F=3072).  All inputs fp32; internal GEMMs in bf16 MFMA.
// R2: 256x256 BK=64 double-buffered 2-phase GEMM (8 waves), XCD swizzle,
//     wave-per-row LayerNorm.
// ---------------------------------------------------------------------------

typedef __attribute__((ext_vector_type(8))) short  short8;
typedef __attribute__((ext_vector_type(4))) float  float4v;
typedef __attribute__((ext_vector_type(4))) unsigned short ushort4v;
typedef unsigned short ushort;

#define DEV static __device__ __forceinline__

DEV ushort f2bf(float f) {
  union { float f; unsigned u; } v; v.f = f;
  unsigned r = v.u + 0x7fffu + ((v.u >> 16) & 1u);   // RNE
  return (ushort)(r >> 16);
}
DEV float bf2f(ushort h) {
  union { unsigned u; float f; } v; v.u = ((unsigned)h) << 16;
  return v.f;
}

DEV void gld_lds16(const void* g, void* l) {
  __builtin_amdgcn_global_load_lds(
      (const __attribute__((address_space(1))) void*)g,
      (__attribute__((address_space(3))) void*)l, 16, 0, 0);
}

// ---------------------------------------------------------------------------
// fp32 -> bf16 weight conversion
__global__ void wcvt(const float* __restrict__ in, ushort* __restrict__ out, int n4) {
  int i = blockIdx.x * 256 + threadIdx.x;
  if (i >= n4) return;
  float4 f = *((const float4*)in + i);
  ushort4v o;
  o[0] = f2bf(f.x); o[1] = f2bf(f.y); o[2] = f2bf(f.z); o[3] = f2bf(f.w);
  *(ushort4v*)(out + (size_t)i * 4) = o;
}

// ---------------------------------------------------------------------------
// LayerNorm over 768, one WAVE per row (4 rows/block); writes bf16.
__global__ __launch_bounds__(256) void ln_k(const float* __restrict__ x,
                                            const float* __restrict__ w,
                                            const float* __restrict__ b,
                                            ushort* __restrict__ out) {
  int wid = threadIdx.x >> 6, lane = threadIdx.x & 63;
  int row = blockIdx.x * 4 + wid;
  size_t base = (size_t)row * 768;
  const float4* xr = (const float4*)(x + base);
  const float4* w4 = (const float4*)w;
  const float4* b4 = (const float4*)b;
  float4 v[3];
  float s = 0.f, q = 0.f;
#pragma unroll
  for (int j = 0; j < 3; ++j) {
    v[j] = xr[j * 64 + lane];
    s += v[j].x + v[j].y + v[j].z + v[j].w;
    q += v[j].x * v[j].x + v[j].y * v[j].y + v[j].z * v[j].z + v[j].w * v[j].w;
  }
#pragma unroll
  for (int m = 1; m < 64; m <<= 1) { s += __shfl_xor(s, m); q += __shfl_xor(q, m); }
  float mean = s * (1.f / 768.f);
  float var  = q * (1.f / 768.f) - mean * mean;
  float rstd = rsqrtf(var + 1e-6f);
  ushort* orow = out + base;
#pragma unroll
  for (int j = 0; j < 3; ++j) {
    float4 wv = w4[j * 64 + lane], bv = b4[j * 64 + lane];
    ushort4v o;
    o[0] = f2bf((v[j].x - mean) * rstd * wv.x + bv.x);
    o[1] = f2bf((v[j].y - mean) * rstd * wv.y + bv.y);
    o[2] = f2bf((v[j].z - mean) * rstd * wv.z + bv.z);
    o[3] = f2bf((v[j].w - mean) * rstd * wv.w + bv.w);
    *(ushort4v*)(orow + (size_t)(j * 64 + lane) * 4) = o;
  }
}

// ---------------------------------------------------------------------------
// conv1d (k=3, pad=1) over T=4 per-frame CLS tokens, both convq and convk.
__global__ __launch_bounds__(256) void conv_cls(const ushort* __restrict__ h,
                                                const float* __restrict__ wq,
                                                const float* __restrict__ wk,
                                                float* __restrict__ cq,
                                                float* __restrict__ ck) {
  __shared__ float gsh[16][6][48];       // [video][t (0,5 zero-pad)][ci]
  int tid = threadIdx.x;
  int cc = blockIdx.x;                   // cout chunk
  int kc = blockIdx.y;                   // ci chunk
  for (int idx = tid; idx < 16 * 2 * 48; idx += 256) {
    int ci = idx % 48; int t = (idx / 48) & 1; int v = idx / 96;
    gsh[v][t * 5][ci] = 0.f;
  }
  for (int idx = tid; idx < 16 * 4 * 48; idx += 256) {
    int ci = idx % 48; int t = (idx / 48) & 3; int v = idx / 192;
    gsh[v][t + 1][ci] = bf2f(h[(size_t)(v * 4 + t) * 197 * 768 + kc * 48 + ci]);
  }
  __syncthreads();
  int cl = tid >> 2, t = tid & 3;
  int cout = cc * 64 + cl;
  const float* wqp = wq + ((size_t)cout * 768 + kc * 48) * 3;
  const float* wkp = wk + ((size_t)cout * 768 + kc * 48) * 3;
  float aq[16] = {}, ak[16] = {};
  for (int ci = 0; ci < 48; ++ci) {
    float q0 = wqp[ci * 3], q1 = wqp[ci * 3 + 1], q2 = wqp[ci * 3 + 2];
    float k0 = wkp[ci * 3], k1 = wkp[ci * 3 + 1], k2 = wkp[ci * 3 + 2];
#pragma unroll
    for (int v = 0; v < 16; ++v) {
      float g0 = gsh[v][t][ci], g1 = gsh[v][t + 1][ci], g2 = gsh[v][t + 2][ci];
      aq[v] += q0 * g0 + q1 * g1 + q2 * g2;
      ak[v] += k0 * g0 + k1 * g1 + k2 * g2;
    }
  }
#pragma unroll
  for (int v = 0; v < 16; ++v) {
    atomicAdd(&cq[(size_t)(v * 4 + t) * 768 + cout], aq[v]);
    atomicAdd(&ck[(size_t)(v * 4 + t) * 768 + cout], ak[v]);
  }
}

// ---------------------------------------------------------------------------
// 256x256 bf16 MFMA GEMM, BK=64, 512 threads (8 waves, 2Mx4N), double-buffered
// LDS with 2-phase overlap (stage t+1 issued before compute of t; single
// __syncthreads per K-tile = vmcnt drain + barrier).  8-chunk XOR swizzle.
// C[M,N] = A[M,K] @ W[N,K]^T + bias.
// EPI: 0 = QKV scatter (+cq/+ck), 1 = proj (+res -> f32), 2 = FF1 (+GELU ->
// bf16), 3 = FF2 (+res -> f32 out).
template <int EPI>
__global__ __launch_bounds__(512, 2) void gemm256(
    const ushort* __restrict__ A, const ushort* __restrict__ W,
    int M, int N, int K, int mt, const float* __restrict__ bias,
    float* __restrict__ out_f, ushort* __restrict__ out_h,
    const float* __restrict__ res,
    const float* __restrict__ cq, const float* __restrict__ ck,
    const float* __restrict__ cqb, const float* __restrict__ ckb,
    ushort* __restrict__ Qo, ushort* __restrict__ Ko, ushort* __restrict__ Vo) {
  __shared__ ushort As[2][256 * 64];   // 32 KB each
  __shared__ ushort Bs[2][256 * 64];   // total 128 KB

  // XCD-chunked block swizzle (bijective, m204) + row-fastest within chunk
  int nwg = gridDim.x;
  int bid = blockIdx.x;
  int q8 = nwg >> 3, r8 = nwg & 7;
  int xcd = bid & 7, idx = bid >> 3;
  int wg = (xcd < r8 ? xcd * (q8 + 1) : r8 * (q8 + 1) + (xcd - r8) * q8) + idx;
  int tileCol = wg / mt;
  int tileRow = wg - tileCol * mt;

  long rowBase = (long)tileRow * 256;
  int  colBase = tileCol * 256;

  int tid = threadIdx.x;
  int wid = tid >> 6, lane = tid & 63;
  int wr = wid >> 2, wc = wid & 3;         // 2 x 4 wave grid
  int cG = lane >> 4, cl = lane & 15;

  // staging source pointers (4 x 16B per matrix per K-tile per thread)
  const ushort* asrc[4];
  const ushort* wsrc[4];
  int dstoff[4];
#pragma unroll
  for (int j = 0; j < 4; ++j) {
    int flat = j * 512 + tid;              // 0..2047
    int r = flat >> 3, c = flat & 7;       // row in tile, 16B chunk
    long ar = rowBase + r; if (ar > M - 1) ar = M - 1;
    asrc[j] = A + ar * (size_t)K + (c ^ (r & 7)) * 8;
    wsrc[j] = W + (size_t)(colBase + r) * K + (c ^ (r & 7)) * 8;
    dstoff[j] = flat * 8;                  // shorts
  }

  float4v acc[8][4] = {};

  // prologue: stage K-tile 0 into buffer 0
#pragma unroll
  for (int j = 0; j < 4; ++j) {
    gld_lds16(asrc[j], &As[0][0] + dstoff[j]);
    gld_lds16(wsrc[j], &Bs[0][0] + dstoff[j]);
  }
  __syncthreads();

  int nt = K >> 6;
  for (int t = 0; t < nt; ++t) {
    const ushort* as = &As[t & 1][0];
    const ushort* bs = &Bs[t & 1][0];
    if (t + 1 < nt) {
      ushort* an = &As[(t + 1) & 1][0];
      ushort* bn = &Bs[(t + 1) & 1][0];
      int kt = (t + 1) << 6;
#pragma unroll
      for (int j = 0; j < 4; ++j) {
        gld_lds16(asrc[j] + kt, an + dstoff[j]);
        gld_lds16(wsrc[j] + kt, bn + dstoff[j]);
      }
    }
    // compute K-tile t
#pragma unroll
    for (int ks = 0; ks < 2; ++ks) {
      short8 bfv[4];
#pragma unroll
      for (int fj = 0; fj < 4; ++fj) {
        int r = wc * 64 + fj * 16 + cl;
        bfv[fj] = *(const short8*)(bs + r * 64 + (((ks << 2) | cG) ^ (r & 7)) * 8);
      }
#pragma unroll
      for (int fi = 0; fi < 8; ++fi) {
        int r = wr * 128 + fi * 16 + cl;
        short8 av = *(const short8*)(as + r * 64 + (((ks << 2) | cG) ^ (r & 7)) * 8);
#pragma unroll
        for (int fj = 0; fj < 4; ++fj)
          acc[fi][fj] = __builtin_amdgcn_mfma_f32_16x16x32_bf16(av, bfv[fj], acc[fi][fj], 0, 0, 0);
      }
    }
    __syncthreads();   // vmcnt(0)+lgkmcnt(0) drain + barrier: t+1 resident, WAR safe
  }

  // epilogue: D col = lane&15, row = 4*(lane>>4)+j
#pragma unroll
  for (int fi = 0; fi < 8; ++fi) {
    long r0 = rowBase + wr * 128 + fi * 16 + 4 * cG;
#pragma unroll
    for (int fj = 0; fj < 4; ++fj) {
      int col = colBase + wc * 64 + fj * 16 + cl;
      float bc = bias[col];
      float4v a = acc[fi][fj];
#pragma unroll
      for (int j = 0; j < 4; ++j) {
        long row = r0 + j;
        if (row >= M) continue;
        float v = a[j] + bc;
        if constexpr (EPI == 0) {
          int sec = col / 768; int ccc = col - sec * 768;
          int bi = (int)(row / 197); int ni = (int)(row - (long)bi * 197);
          size_t oidx = ((size_t)(bi * 12 + (ccc >> 6)) * 197 + ni) * 64 + (ccc & 63);
          if (sec == 0)      { v += cq[bi * 768 + ccc] + cqb[ccc]; Qo[oidx] = f2bf(v); }
          else if (sec == 1) { v += ck[bi * 768 + ccc] + ckb[ccc]; Ko[oidx] = f2bf(v); }
          else               { Vo[oidx] = f2bf(v); }
        } else if constexpr (EPI == 1 || EPI == 3) {
          size_t idx = (size_t)row * N + col;
          out_f[idx] = v + res[idx];
        } else {
          size_t idx = (size_t)row * N + col;
          float g = 0.5f * v * (1.0f + erff(v * 0.70710678118f));
          out_h[idx] = f2bf(g);
        }
      }
    }
  }
}

// ---------------------------------------------------------------------------
// Attention: one block (4 waves) per (b,h).  N=197 padded to 224 in LDS.
__global__ __launch_bounds__(256, 2) void attn_k(const ushort* __restrict__ Q,
                                                 const ushort* __restrict__ Kg,
                                                 const ushort* __restrict__ Vg,
                                                 ushort* __restrict__ O) {
  __shared__ ushort Ks[224 * 64];   // [n][d], chunk ^= n&7
  __shared__ ushort Vt[64 * 224];   // [d][n], n-block ^= (d&7)<<3
  __shared__ ushort Ps[4][16 * 40]; // per-wave P chunk [16][32+pad8]
  int g = blockIdx.x;
  int bi = g / 12, hh = g - bi * 12;
  size_t gbase = (size_t)g * 197 * 64;
  int tid = threadIdx.x, wid = tid >> 6, lane = tid & 63;
  int cG = lane >> 4, cl = lane & 15;

  {
    int rr = tid >> 3, ch = tid & 7;
#pragma unroll
    for (int i = 0; i < 7; ++i) {
      int n = rr + 32 * i;
      short8 kv = {0, 0, 0, 0, 0, 0, 0, 0};
      if (n < 197) kv = *(const short8*)(Kg + gbase + (size_t)n * 64 + ch * 8);
      *(short8*)(Ks + n * 64 + (ch ^ (n & 7)) * 8) = kv;
      short8 vv = {0, 0, 0, 0, 0, 0, 0, 0};
      if (n < 197) vv = *(const short8*)(Vg + gbase + (size_t)n * 64 + ch * 8);
#pragma unroll
      for (int j = 0; j < 8; ++j) {
        int dd = ch * 8 + j;
        Vt[dd * 224 + (n ^ ((dd & 7) << 3))] = ((ushort*)&vv)[j];
      }
    }
  }
  __syncthreads();

  for (int rt = wid; rt < 13; rt += 4) {
    int nq = rt * 16 + cl; if (nq > 196) nq = 196;
    short8 aq0 = *(const short8*)(Q + gbase + (size_t)nq * 64 + 8 * cG);
    short8 aq1 = *(const short8*)(Q + gbase + (size_t)nq * 64 + 32 + 8 * cG);
    float4v s[14];
#pragma unroll
    for (int ct = 0; ct < 14; ++ct) {
      float4v a = {0.f, 0.f, 0.f, 0.f};
      int np = ct * 16 + cl;
      short8 b0 = *(const short8*)(Ks + np * 64 + ((cG    ) ^ (np & 7)) * 8);
      short8 b1 = *(const short8*)(Ks + np * 64 + ((4 + cG) ^ (np & 7)) * 8);
      a = __builtin_amdgcn_mfma_f32_16x16x32_bf16(aq0, b0, a, 0, 0, 0);
      a = __builtin_amdgcn_mfma_f32_16x16x32_bf16(aq1, b1, a, 0, 0, 0);
      s[ct] = a;
    }
    float mx[4] = {-1e30f, -1e30f, -1e30f, -1e30f};
#pragma unroll
    for (int ct = 0; ct < 14; ++ct) {
      int colv = ct * 16 + cl;
#pragma unroll
      for (int j = 0; j < 4; ++j) {
        float v = (colv < 197) ? s[ct][j] * 0.125f : -1e30f;
        s[ct][j] = v;
        mx[j] = fmaxf(mx[j], v);
      }
    }
#pragma unroll
    for (int m = 1; m < 16; m <<= 1)
#pragma unroll
      for (int j = 0; j < 4; ++j) mx[j] = fmaxf(mx[j], __shfl_xor(mx[j], m));
    float sum[4] = {0.f, 0.f, 0.f, 0.f};
#pragma unroll
    for (int ct = 0; ct < 14; ++ct)
#pragma unroll
      for (int j = 0; j < 4; ++j) {
        float p = __expf(s[ct][j] - mx[j]);
        s[ct][j] = p;
        sum[j] += p;
      }
#pragma unroll
    for (int m = 1; m < 16; m <<= 1)
#pragma unroll
      for (int j = 0; j < 4; ++j) sum[j] += __shfl_xor(sum[j], m);
    float rs[4];
#pragma unroll
    for (int j = 0; j < 4; ++j) rs[j] = 1.0f / sum[j];

    float4v oa[4] = {};
    ushort* P = &Ps[wid][0];
#pragma unroll
    for (int ks = 0; ks < 7; ++ks) {
#pragma unroll
      for (int t = 0; t < 2; ++t) {
        int ct = 2 * ks + t;
#pragma unroll
        for (int j = 0; j < 4; ++j)
          P[(4 * cG + j) * 40 + t * 16 + cl] = f2bf(s[ct][j]);
      }
      short8 pa = *(const short8*)(P + cl * 40 + 8 * cG);
#pragma unroll
      for (int dt = 0; dt < 4; ++dt) {
        int dd = dt * 16 + cl;
        short8 bv = *(const short8*)(Vt + dd * 224 + ((ks * 32 + 8 * cG) ^ ((dd & 7) << 3)));
        oa[dt] = __builtin_amdgcn_mfma_f32_16x16x32_bf16(pa, bv, oa[dt], 0, 0, 0);
      }
    }
#pragma unroll
    for (int dt = 0; dt < 4; ++dt)
#pragma unroll
      for (int j = 0; j < 4; ++j) {
        int n2 = rt * 16 + 4 * cG + j;
        if (n2 < 197)
          O[(size_t)(bi * 197 + n2) * 768 + hh * 64 + dt * 16 + cl] = f2bf(oa[dt][j] * rs[j]);
      }
  }
}

// ---------------------------------------------------------------------------
extern "C" void kernel_launch(void* const* d_in, const int* in_sizes, int n_in,
                              void* d_out, int out_size, void* d_ws, size_t ws_size,
                              hipStream_t stream) {
  const float* x     = (const float*)d_in[0];
  const float* ln1w  = (const float*)d_in[1];
  const float* ln1b  = (const float*)d_in[2];
  const float* qkvw  = (const float*)d_in[3];
  const float* qkvb  = (const float*)d_in[4];
  const float* cqw   = (const float*)d_in[5];
  const float* cqb   = (const float*)d_in[6];
  const float* ckw   = (const float*)d_in[7];
  const float* ckb   = (const float*)d_in[8];
  const float* projw = (const float*)d_in[9];
  const float* projb = (const float*)d_in[10];
  const float* ln2w  = (const float*)d_in[11];
  const float* ln2b  = (const float*)d_in[12];
  const float* ff1w  = (const float*)d_in[13];
  const float* ff1b  = (const float*)d_in[14];
  const float* ff2w  = (const float*)d_in[15];
  const float* ff2b  = (const float*)d_in[16];
  float* out = (float*)d_out;

  char* ws = (char*)d_ws;
  const size_t SZ = (size_t)12608 * 768 * 2;          // 19,365,888 B
  ushort* Qb  = (ushort*)(ws);
  ushort* Kb  = (ushort*)(ws + SZ);
  ushort* Vb  = (ushort*)(ws + 2 * SZ);
  ushort* Ob  = (ushort*)(ws + 3 * SZ);
  ushort* ffh = (ushort*)(ws);        // overlays Q..O after proj
  ushort* hb  = (ushort*)(ws + 4 * SZ);
  float* x1 = (float*)(ws + 5 * SZ);
  float* cq = (float*)(ws + 5 * SZ + (size_t)12608 * 768 * 4);
  float* ck = cq + 49152;
  ushort* Wqkv  = (ushort*)(ck + 49152);
  ushort* Wproj = Wqkv + 1769472;
  ushort* Wff1  = Wproj + 589824;
  ushort* Wff2  = Wff1 + 2359296;

  // weights -> bf16 (inputs restored every timed call, so convert every call)
  wcvt<<<1728, 256, 0, stream>>>(qkvw, Wqkv, 442368);
  wcvt<<<576,  256, 0, stream>>>(projw, Wproj, 147456);
  wcvt<<<2304, 256, 0, stream>>>(ff1w, Wff1, 589824);
  wcvt<<<2304, 256, 0, stream>>>(ff2w, Wff2, 589824);

  // LN1
  ln_k<<<3152, 256, 0, stream>>>(x, ln1w, ln1b, hb);

  // temporal conv on CLS tokens
  hipMemsetAsync(cq, 0, 2 * 49152 * sizeof(float), stream);
  conv_cls<<<dim3(12, 16), 256, 0, stream>>>(hb, cqw, ckw, cq, ck);

  // QKV projection (+cq/+ck fold, scatter to (b*12+h, n, d)); M-tiles=50, N-tiles=9
  gemm256<0><<<450, 512, 0, stream>>>(hb, Wqkv, 12608, 2304, 768, 50, qkvb,
      nullptr, nullptr, nullptr, cq, ck, cqb, ckb, Qb, Kb, Vb);

  // attention
  attn_k<<<768, 256, 0, stream>>>(Qb, Kb, Vb, Ob);

  // output projection + residual -> x1 (f32); N-tiles=3
  gemm256<1><<<150, 512, 0, stream>>>(Ob, Wproj, 12608, 768, 768, 50, projb,
      x1, nullptr, x, nullptr, nullptr, nullptr, nullptr, nullptr, nullptr, nullptr);

  // LN2
  ln_k<<<3152, 256, 0, stream>>>(x1, ln2w, ln2b, hb);

  // FF1 + GELU -> bf16; N-tiles=12
  gemm256<2><<<600, 512, 0, stream>>>(hb, Wff1, 12608, 3072, 768, 50, ff1b,
      nullptr, ffh, nullptr, nullptr, nullptr, nullptr, nullptr, nullptr, nullptr, nullptr);

  // FF2 + residual -> out (f32); N-tiles=3
  gemm256<3><<<150, 512, 0, stream>>>(ffh, Wff2, 12608, 768, 3072, 50, ff2b,
      out, nullptr, x1, nullptr, nullptr, nullptr, nullptr, nullptr, nullptr, nullptr);
}